// Round 1
// baseline (394.255 us; speedup 1.0000x reference)
//
#include <hip/hip_runtime.h>
#include <hip/hip_bf16.h>
#include <math.h>

#define BB 4
#define TT 2048
#define CC 768
#define NHD 16
#define HD 48
#define NQT 32  // TT/64

typedef __hip_bfloat16 bf16;
typedef __attribute__((ext_vector_type(8))) short short8;
typedef __attribute__((ext_vector_type(4))) float floatx4;

__device__ __forceinline__ unsigned short f2bf(float x) {
    bf16 h = __float2bfloat16(x);
    return *(unsigned short*)&h;
}
__device__ __forceinline__ float bfu2f(unsigned short u) {
    return __uint_as_float(((unsigned)u) << 16);
}

// async global->LDS, 16B per lane; LDS dest = wave-uniform base + lane*16
__device__ __forceinline__ void gl_lds16(const void* g, void* s) {
    __builtin_amdgcn_global_load_lds((const __attribute__((address_space(1))) void*)g,
                                     (__attribute__((address_space(3))) void*)s, 16, 0, 0);
}

// pack two fp32 -> packed bf16 pair (round-half-up; inputs are probabilities >= 0)
__device__ __forceinline__ unsigned int pk_bf2(float a, float b) {
    unsigned int ua = __float_as_uint(a) + 0x8000u;
    unsigned int ub = __float_as_uint(b) + 0x8000u;
    return __builtin_amdgcn_perm(ub, ua, 0x07060302);
}

// ---------- fp32 -> bf16 casts ----------
__global__ __launch_bounds__(256) void cast_hs(const float* __restrict__ src,
                                               unsigned short* __restrict__ dst) {
    int i = (blockIdx.x * 256 + threadIdx.x) * 4;
    float4 v = *(const float4*)(src + i);
    ushort4 p;
    p.x = f2bf(v.x); p.y = f2bf(v.y); p.z = f2bf(v.z); p.w = f2bf(v.w);
    *(ushort4*)(dst + i) = p;
}

__global__ __launch_bounds__(256) void cast_w4(const float* __restrict__ s0, const float* __restrict__ s1,
                                               const float* __restrict__ s2, const float* __restrict__ s3,
                                               unsigned short* __restrict__ d0, unsigned short* __restrict__ d1,
                                               unsigned short* __restrict__ d2, unsigned short* __restrict__ d3) {
    const float* s; unsigned short* d;
    switch (blockIdx.y) {
        case 0: s = s0; d = d0; break;
        case 1: s = s1; d = d1; break;
        case 2: s = s2; d = d2; break;
        default: s = s3; d = d3; break;
    }
    int i = (blockIdx.x * 256 + threadIdx.x) * 4;
    float4 v = *(const float4*)(s + i);
    ushort4 p;
    p.x = f2bf(v.x); p.y = f2bf(v.y); p.z = f2bf(v.z); p.w = f2bf(v.w);
    *(ushort4*)(d + i) = p;
}

// ---------- RoPE sincos table: tab[t][p] = {cos, sin}, p in [0,24) ----------
__global__ __launch_bounds__(256) void rope_table(float2* __restrict__ tab) {
    int idx = blockIdx.x * 256 + threadIdx.x;  // over 2048*24
    int t = idx / 24, p = idx % 24;
    float inv_freq = powf(10000.0f, -((float)(2 * p) / (float)HD));
    float ang = (float)t * inv_freq;
    float sn, cs;
    sincosf(ang, &sn, &cs);
    tab[idx] = make_float2(cs, sn);
}

// ---------- bf16 MFMA NT-GEMM, BK=64, lds-direct staging with XOR-swizzle ----------
// 1-D grid, XCD-swizzled: bx -> (xcd = bx&7, slot = bx>>3); x = slot % NXB,
// y = (slot/NXB)*8 + xcd  => all blocks sharing an A row-band (same y) land on
// one XCD so the A-tile is fetched once per XCD-L2, not 8x.
// MODE 0: N=768 (NXB=6), fp32 row-major out. MODE 1: fused QKV N=2304 (NXB=18).
template <int MODE>
__global__ __launch_bounds__(256) void gemm_mfma(const unsigned short* __restrict__ A,
                                                 const unsigned short* __restrict__ Bw,
                                                 const float* __restrict__ b0p,
                                                 const float* __restrict__ b1p,
                                                 const float* __restrict__ b2p,
                                                 void* __restrict__ out0,
                                                 void* __restrict__ out1,
                                                 void* __restrict__ out2) {
    __shared__ __align__(16) unsigned short As[128][64];
    __shared__ __align__(16) unsigned short Bs[128][64];
    const int tid = threadIdx.x;
    const int w = tid >> 6, lane = tid & 63;
    const int quad = lane >> 4, ln = lane & 15;
    const int wr = w >> 1, wc = w & 1;

    const int NXB = (MODE == 1) ? 18 : 6;
    const int bx = blockIdx.x;
    const int xcd = bx & 7, slot = bx >> 3;
    const int n0 = (slot % NXB) * 128;
    const int m0 = ((slot / NXB) * 8 + xcd) * 128;

    const int srow = lane >> 3;
    const int ssw = ((lane & 7) ^ srow) * 8;
    const unsigned short* agp[4];
    const unsigned short* bgp[4];
    void* asl[4];
    void* bsl[4];
#pragma unroll
    for (int i = 0; i < 4; ++i) {
        const int R = i * 32 + w * 8;
        agp[i] = A + (size_t)(m0 + R + srow) * CC + ssw;
        bgp[i] = Bw + (size_t)(n0 + R + srow) * CC + ssw;
        asl[i] = &As[R][0];
        bsl[i] = &Bs[R][0];
    }

    floatx4 acc[4][4];
#pragma unroll
    for (int mi = 0; mi < 4; ++mi)
#pragma unroll
        for (int ni = 0; ni < 4; ++ni) acc[mi][ni] = (floatx4){0.f, 0.f, 0.f, 0.f};

    const int ps0 = (quad ^ (ln & 7)) * 8;

    for (int k0 = 0; k0 < CC; k0 += 64) {
        __syncthreads();
#pragma unroll
        for (int i = 0; i < 4; ++i) {
            gl_lds16(agp[i] + k0, asl[i]);
            gl_lds16(bgp[i] + k0, bsl[i]);
        }
        __syncthreads();
#pragma unroll
        for (int kh = 0; kh < 2; ++kh) {
            const int ps = ps0 ^ (kh * 32);
            short8 af[4], bfr[4];
#pragma unroll
            for (int mi = 0; mi < 4; ++mi)
                af[mi] = *(const short8*)&As[wr * 64 + mi * 16 + ln][ps];
#pragma unroll
            for (int ni = 0; ni < 4; ++ni)
                bfr[ni] = *(const short8*)&Bs[wc * 64 + ni * 16 + ln][ps];
#pragma unroll
            for (int mi = 0; mi < 4; ++mi)
#pragma unroll
                for (int ni = 0; ni < 4; ++ni)
                    acc[mi][ni] = __builtin_amdgcn_mfma_f32_16x16x32_bf16(af[mi], bfr[ni], acc[mi][ni], 0, 0, 0);
        }
    }

    if (MODE == 0) {
        float* outf = (float*)out0;
        float bv[4];
#pragma unroll
        for (int ni = 0; ni < 4; ++ni) bv[ni] = b0p[n0 + wc * 64 + ni * 16 + ln];
#pragma unroll
        for (int mi = 0; mi < 4; ++mi)
#pragma unroll
            for (int r = 0; r < 4; ++r) {
                size_t row = m0 + wr * 64 + mi * 16 + quad * 4 + r;
#pragma unroll
                for (int ni = 0; ni < 4; ++ni)
                    outf[row * CC + n0 + wc * 64 + ni * 16 + ln] = acc[mi][ni][r] + bv[ni];
            }
    } else {
        const int seg = n0 / CC;
        const int nl0 = n0 - seg * CC;
        const float* bp = (seg == 0) ? b0p : (seg == 1) ? b1p : b2p;
        float bv[4];
#pragma unroll
        for (int ni = 0; ni < 4; ++ni) bv[ni] = bp[nl0 + wc * 64 + ni * 16 + ln];

        if (seg < 2) {
            unsigned short* outb = (unsigned short*)(seg == 0 ? out0 : out1);
#pragma unroll
            for (int mi = 0; mi < 4; ++mi)
#pragma unroll
                for (int r = 0; r < 4; ++r) {
                    size_t row = m0 + wr * 64 + mi * 16 + quad * 4 + r;
#pragma unroll
                    for (int ni = 0; ni < 4; ++ni)
                        outb[row * CC + nl0 + wc * 64 + ni * 16 + ln] = f2bf(acc[mi][ni][r] + bv[ni]);
                }
        } else {
            unsigned short* outb = (unsigned short*)out2;
            const int b = m0 >> 11;
#pragma unroll
            for (int ni = 0; ni < 4; ++ni) {
                int col = nl0 + wc * 64 + ni * 16 + ln;
                int h = col / HD, d = col % HD;
                size_t base = (size_t)((b * NHD + h) * HD + d) * TT;
#pragma unroll
                for (int mi = 0; mi < 4; ++mi) {
                    int t = (m0 & 2047) + wr * 64 + mi * 16 + quad * 4;
                    ushort4 pk;
                    pk.x = f2bf(acc[mi][ni][0] + bv[ni]);
                    pk.y = f2bf(acc[mi][ni][1] + bv[ni]);
                    pk.z = f2bf(acc[mi][ni][2] + bv[ni]);
                    pk.w = f2bf(acc[mi][ni][3] + bv[ni]);
                    *(ushort4*)(outb + base + t) = pk;
                }
            }
        }
    }
}

// RoPE in-place via precomputed table, vectorized: each thread handles 8
// rotary pairs (short8 loads/stores). q pre-scaled by (1/sqrt(48))*log2(e).
__global__ __launch_bounds__(256) void rope_bf(unsigned short* __restrict__ q,
                                               unsigned short* __restrict__ k,
                                               const float2* __restrict__ tab) {
    int idx = blockIdx.x * blockDim.x + threadIdx.x;  // over B*T*H*3
    const int HALF = HD / 2;
    int p8 = idx % 3;          // which group of 8 pairs
    int rest = idx / 3;
    int h = rest % NHD;
    int n = rest / NHD;        // b*T + t
    int t = n & (TT - 1);
    const float QSC = 0.14433756729740643f * 1.4426950408889634f;
    size_t base = (size_t)n * CC + h * HD + p8 * 8;
    const float2* tp = tab + t * HALF + p8 * 8;

    short8 q1 = *(const short8*)(q + base);
    short8 q2 = *(const short8*)(q + base + HALF);
    short8 k1 = *(const short8*)(k + base);
    short8 k2 = *(const short8*)(k + base + HALF);
    short8 r1, r2, s1, s2;
#pragma unroll
    for (int jj = 0; jj < 8; ++jj) {
        float2 cssn = tp[jj];
        float cs = cssn.x, sn = cssn.y;
        float a = bfu2f((unsigned short)q1[jj]), bb = bfu2f((unsigned short)q2[jj]);
        r1[jj] = (short)f2bf((a * cs - bb * sn) * QSC);
        r2[jj] = (short)f2bf((bb * cs + a * sn) * QSC);
        float c2 = bfu2f((unsigned short)k1[jj]), d2 = bfu2f((unsigned short)k2[jj]);
        s1[jj] = (short)f2bf(c2 * cs - d2 * sn);
        s2[jj] = (short)f2bf(d2 * cs + c2 * sn);
    }
    *(short8*)(q + base) = r1;
    *(short8*)(q + base + HALF) = r2;
    *(short8*)(k + base) = s1;
    *(short8*)(k + base + HALF) = s2;
}

// MFMA flash attention, exp2-domain, fixed softmax reference (m=0).
// LDS-traffic-minimized: only K (mask-column trick) and the P transpose
// buffer live in LDS; Q and V fragments are loaded straight from global
// (L1/L2-resident; V tile is shared by all 4 waves and 32 blocks per (b,h)
// pinned to one XCD). LDS = 18.7 KB, target VGPR<=64 -> 8 blocks/CU.
// Grid 2048: one 64-row q-tile per block, zig-zag qt order so adjacent
// blocks pair heavy+light tiles for per-CU load balance.
__global__ __launch_bounds__(256, 8) void attn_kernel(const unsigned short* __restrict__ qb,
                                                      const unsigned short* __restrict__ kb,
                                                      const unsigned short* __restrict__ vt,
                                                      const float* __restrict__ amask,
                                                      unsigned short* __restrict__ ctx) {
    const int bx = blockIdx.x;
    const int xcd = bx & 7;
    const int rem = bx >> 3;             // [0,256)
    const int u = rem & 31;              // zig-zag qt index
    const int qt = (u & 1) ? (31 - (u >> 1)) : (u >> 1);
    const int j = ((rem >> 5) << 3) | xcd;  // (b,h) group, grouped per XCD
    const int b = j >> 4, h = j & 15;
    const int tid = threadIdx.x;
    const int w = tid >> 6, lane = tid & 63;
    const int g = lane >> 4, ln = lane & 15;

    __shared__ __align__(16) unsigned short Ks[64][72];
    __shared__ __align__(16) unsigned short Pw[4][16][72];
    __shared__ __align__(16) float l_s[4][16];

    const short8 z8 = {0, 0, 0, 0, 0, 0, 0, 0};
    const short8 ones8 = {0x3F80, 0x3F80, 0x3F80, 0x3F80, 0x3F80, 0x3F80, 0x3F80, 0x3F80};

    // zero Ks pad columns 48..63 once (col 48 is rewritten with mask each step)
    if (tid < 128) {
        int r = tid >> 1, half = tid & 1;
        *(short8*)&Ks[r][48 + half * 8] = z8;
    }

    const int ck1 = tid + 256;
    const int rK0 = tid / 6, sK0 = tid % 6;
    const int rK1 = ck1 / 6, sK1 = ck1 % 6;
    const unsigned short* kp0 = kb + (size_t)(b * TT + rK0) * CC + h * HD + sK0 * 8;
    const unsigned short* kp1 = kb + (size_t)(b * TT + rK1) * CC + h * HD + sK1 * 8;
    const float* mp = amask + b * TT + (tid & 63);
    const float MBS = -10000.0f * 1.4426950408889634f;

    // V direct-load pointers: d-row = n*16+ln, col offset g*8, advance 64/step
    const unsigned short* vp0 = vt + ((size_t)((b * NHD + h) * HD) + 0 * 16 + ln) * TT + g * 8;
    const unsigned short* vp1 = vt + ((size_t)((b * NHD + h) * HD) + 1 * 16 + ln) * TT + g * 8;
    const unsigned short* vp2 = vt + ((size_t)((b * NHD + h) * HD) + 2 * 16 + ln) * TT + g * 8;
    const short8 vone = (ln == 0) ? ones8 : z8;  // ones-row fragment (l accumulator)

    const int q0 = qt * 64;

    // Q fragments: straight from global into registers; mask column (48) is
    // a constant {1.0, 0...} fragment on the g==2 quad.
    const unsigned short* qrow = qb + (size_t)(b * TT + q0 + w * 16 + ln) * CC + h * HD;
    short8 aq0 = *(const short8*)(qrow + g * 8);
    short8 aq1;
    if (g < 2) {
        aq1 = *(const short8*)(qrow + 32 + g * 8);
    } else {
        aq1 = z8;
        if (g == 2) aq1[0] = (short)0x3F80;
    }

    short8 kr0, kr1;
    float mr = 1.0f;
    kr0 = *(const short8*)kp0;
    if (tid < 128) kr1 = *(const short8*)kp1;
    if (tid < 64) mr = *mp;

    const int q_lane = q0 + w * 16 + ln;
    floatx4 o0 = {0.f, 0.f, 0.f, 0.f}, o1 = o0, o2 = o0, o3 = o0;

    for (int kt = 0; kt <= qt; ++kt) {
        __syncthreads();
        *(short8*)&Ks[rK0][sK0 * 8] = kr0;
        if (tid < 128) *(short8*)&Ks[rK1][sK1 * 8] = kr1;
        if (tid < 64) Ks[tid][48] = f2bf((1.0f - mr) * MBS);
        __syncthreads();

        if (kt < qt) {
            kp0 += (size_t)64 * CC; kr0 = *(const short8*)kp0;
            if (tid < 128) { kp1 += (size_t)64 * CC; kr1 = *(const short8*)kp1; }
            if (tid < 64) { mp += 64; mr = *mp; }
        }

        const int k0 = kt * 64;
        floatx4 sc[4];
#pragma unroll
        for (int c = 0; c < 4; ++c) {
            short8 kf0 = *(const short8*)&Ks[c * 16 + ln][g * 8];
            short8 kf1 = *(const short8*)&Ks[c * 16 + ln][32 + g * 8];
            floatx4 z = {0.f, 0.f, 0.f, 0.f};
            z = __builtin_amdgcn_mfma_f32_16x16x32_bf16(kf0, aq0, z, 0, 0, 0);
            z = __builtin_amdgcn_mfma_f32_16x16x32_bf16(kf1, aq1, z, 0, 0, 0);
            sc[c] = z;
        }

        const bool diag = (kt == qt);
#pragma unroll
        for (int c = 0; c < 4; ++c) {
            float pv[4];
#pragma unroll
            for (int r = 0; r < 4; ++r) {
                float e = __builtin_amdgcn_exp2f(sc[c][r]);
                if (diag && (k0 + c * 16 + g * 4 + r > q_lane)) e = 0.f;
                pv[r] = e;
            }
            uint2 pk;
            pk.x = pk_bf2(pv[0], pv[1]);
            pk.y = pk_bf2(pv[2], pv[3]);
            *(uint2*)&Pw[w][ln][c * 16 + g * 4] = pk;
        }

        // V fragments direct from global (L1-hot: same addrs across 4 waves);
        // issued between Pw write and read so L1 latency overlaps the
        // lgkm turnaround.
        short8 v00 = *(const short8*)vp0;
        short8 v01 = *(const short8*)(vp0 + 32);
        short8 v10 = *(const short8*)vp1;
        short8 v11 = *(const short8*)(vp1 + 32);
        short8 v20 = *(const short8*)vp2;
        short8 v21 = *(const short8*)(vp2 + 32);
        vp0 += 64; vp1 += 64; vp2 += 64;

        short8 pa0 = *(const short8*)&Pw[w][ln][g * 8];
        short8 pa1 = *(const short8*)&Pw[w][ln][32 + g * 8];

        o0 = __builtin_amdgcn_mfma_f32_16x16x32_bf16(pa0, v00, o0, 0, 0, 0);
        o0 = __builtin_amdgcn_mfma_f32_16x16x32_bf16(pa1, v01, o0, 0, 0, 0);
        o1 = __builtin_amdgcn_mfma_f32_16x16x32_bf16(pa0, v10, o1, 0, 0, 0);
        o1 = __builtin_amdgcn_mfma_f32_16x16x32_bf16(pa1, v11, o1, 0, 0, 0);
        o2 = __builtin_amdgcn_mfma_f32_16x16x32_bf16(pa0, v20, o2, 0, 0, 0);
        o2 = __builtin_amdgcn_mfma_f32_16x16x32_bf16(pa1, v21, o2, 0, 0, 0);
        o3 = __builtin_amdgcn_mfma_f32_16x16x32_bf16(pa0, vone, o3, 0, 0, 0);
        o3 = __builtin_amdgcn_mfma_f32_16x16x32_bf16(pa1, vone, o3, 0, 0, 0);
    }

    if (ln == 0) *(floatx4*)&l_s[w][g * 4] = o3;   // per-wave LDS, no barrier
    floatx4 l4 = *(const floatx4*)&l_s[w][g * 4];
#pragma unroll
    for (int r = 0; r < 4; ++r) {
        float inv_l = 1.0f / l4[r];
        int t = q0 + w * 16 + g * 4 + r;
        unsigned short* dst = ctx + (size_t)(b * TT + t) * CC + h * HD;
        dst[ln] = f2bf(o0[r] * inv_l);
        dst[16 + ln] = f2bf(o1[r] * inv_l);
        dst[32 + ln] = f2bf(o2[r] * inv_l);
    }
}

extern "C" void kernel_launch(void* const* d_in, const int* in_sizes, int n_in,
                              void* d_out, int out_size, void* d_ws, size_t ws_size,
                              hipStream_t stream) {
    const float* hs = (const float*)d_in[0];
    const float* amask = (const float*)d_in[1];
    const float* Wq = (const float*)d_in[2];
    const float* bq = (const float*)d_in[3];
    const float* Wk = (const float*)d_in[4];
    const float* bk = (const float*)d_in[5];
    const float* Wv = (const float*)d_in[6];
    const float* bv = (const float*)d_in[7];
    const float* Wo = (const float*)d_in[8];
    const float* bo = (const float*)d_in[9];

    const size_t NELEM = (size_t)BB * TT * CC;  // 6291456
    const size_t WELEM = (size_t)CC * CC;       // 589824
    unsigned short* hb  = (unsigned short*)d_ws;
    unsigned short* qbuf = hb + NELEM;
    unsigned short* kbuf = qbuf + NELEM;
    unsigned short* vtb = kbuf + NELEM;   // bf16 [B,H,D,T]
    unsigned short* ctxb = vtb + NELEM;
    unsigned short* wqb = ctxb + NELEM;   // wq/wk/wv contiguous = stacked [2304][768]
    unsigned short* wkb = wqb + WELEM;
    unsigned short* wvb = wkb + WELEM;
    unsigned short* wob = wvb + WELEM;
    float2* ropetab = (float2*)(wob + WELEM);  // [2048][24]

    cast_hs<<<NELEM / 1024, 256, 0, stream>>>(hs, hb);
    dim3 wgrid(WELEM / 1024, 4);
    cast_w4<<<wgrid, 256, 0, stream>>>(Wq, Wk, Wv, Wo, wqb, wkb, wvb, wob);
    rope_table<<<(TT * (HD / 2)) / 256, 256, 0, stream>>>(ropetab);

    gemm_mfma<1><<<18 * 64, 256, 0, stream>>>(hb, wqb, bq, bk, bv, qbuf, kbuf, vtb);

    int rope_total = BB * TT * NHD * 3;  // 8 pairs per thread
    rope_bf<<<rope_total / 256, 256, 0, stream>>>(qbuf, kbuf, ropetab);

    attn_kernel<<<2048, 256, 0, stream>>>(qbuf, kbuf, vtb, amask, ctxb);

    gemm_mfma<0><<<6 * 64, 256, 0, stream>>>(ctxb, wob, bo, nullptr, nullptr,
                                             (float*)d_out, nullptr, nullptr);
}

// Round 2
// 343.796 us; speedup vs baseline: 1.1468x; 1.1468x over previous
//
#include <hip/hip_runtime.h>
#include <hip/hip_bf16.h>
#include <math.h>

#define BB 4
#define TT 2048
#define CC 768
#define NHD 16
#define HD 48
#define NQT 32  // TT/64

typedef __hip_bfloat16 bf16;
typedef __attribute__((ext_vector_type(8))) short short8;
typedef __attribute__((ext_vector_type(4))) float floatx4;

__device__ __forceinline__ unsigned short f2bf(float x) {
    bf16 h = __float2bfloat16(x);
    return *(unsigned short*)&h;
}
__device__ __forceinline__ float bfu2f(unsigned short u) {
    return __uint_as_float(((unsigned)u) << 16);
}

// async global->LDS, 16B per lane; LDS dest = wave-uniform base + lane*16
__device__ __forceinline__ void gl_lds16(const void* g, void* s) {
    __builtin_amdgcn_global_load_lds((const __attribute__((address_space(1))) void*)g,
                                     (__attribute__((address_space(3))) void*)s, 16, 0, 0);
}

// pack two fp32 -> packed bf16 pair (round-half-up; inputs are probabilities >= 0)
__device__ __forceinline__ unsigned int pk_bf2(float a, float b) {
    unsigned int ua = __float_as_uint(a) + 0x8000u;
    unsigned int ub = __float_as_uint(b) + 0x8000u;
    return __builtin_amdgcn_perm(ub, ua, 0x07060302);
}

// ---------- fp32 -> bf16 casts ----------
__global__ __launch_bounds__(256) void cast_hs(const float* __restrict__ src,
                                               unsigned short* __restrict__ dst) {
    int i = (blockIdx.x * 256 + threadIdx.x) * 4;
    float4 v = *(const float4*)(src + i);
    ushort4 p;
    p.x = f2bf(v.x); p.y = f2bf(v.y); p.z = f2bf(v.z); p.w = f2bf(v.w);
    *(ushort4*)(dst + i) = p;
}

__global__ __launch_bounds__(256) void cast_w4(const float* __restrict__ s0, const float* __restrict__ s1,
                                               const float* __restrict__ s2, const float* __restrict__ s3,
                                               unsigned short* __restrict__ d0, unsigned short* __restrict__ d1,
                                               unsigned short* __restrict__ d2, unsigned short* __restrict__ d3) {
    const float* s; unsigned short* d;
    switch (blockIdx.y) {
        case 0: s = s0; d = d0; break;
        case 1: s = s1; d = d1; break;
        case 2: s = s2; d = d2; break;
        default: s = s3; d = d3; break;
    }
    int i = (blockIdx.x * 256 + threadIdx.x) * 4;
    float4 v = *(const float4*)(s + i);
    ushort4 p;
    p.x = f2bf(v.x); p.y = f2bf(v.y); p.z = f2bf(v.z); p.w = f2bf(v.w);
    *(ushort4*)(d + i) = p;
}

// ---------- RoPE sincos table: tab[t][p] = {cos, sin}, p in [0,24) ----------
__global__ __launch_bounds__(256) void rope_table(float2* __restrict__ tab) {
    int idx = blockIdx.x * 256 + threadIdx.x;  // over 2048*24
    int t = idx / 24, p = idx % 24;
    float inv_freq = powf(10000.0f, -((float)(2 * p) / (float)HD));
    float ang = (float)t * inv_freq;
    float sn, cs;
    sincosf(ang, &sn, &cs);
    tab[idx] = make_float2(cs, sn);
}

// ---------- bf16 MFMA NT-GEMM, BK=64, lds-direct staging with XOR-swizzle ----------
// 1-D grid, XCD-swizzled: bx -> (xcd = bx&7, slot = bx>>3); x = slot % NXB,
// y = (slot/NXB)*8 + xcd  => all blocks sharing an A row-band (same y) land on
// one XCD so the A-tile is fetched once per XCD-L2, not 8x.
// MODE 0: N=768 (NXB=6), fp32 row-major out. MODE 1: fused QKV N=2304 (NXB=18).
template <int MODE>
__global__ __launch_bounds__(256) void gemm_mfma(const unsigned short* __restrict__ A,
                                                 const unsigned short* __restrict__ Bw,
                                                 const float* __restrict__ b0p,
                                                 const float* __restrict__ b1p,
                                                 const float* __restrict__ b2p,
                                                 void* __restrict__ out0,
                                                 void* __restrict__ out1,
                                                 void* __restrict__ out2) {
    __shared__ __align__(16) unsigned short As[128][64];
    __shared__ __align__(16) unsigned short Bs[128][64];
    const int tid = threadIdx.x;
    const int w = tid >> 6, lane = tid & 63;
    const int quad = lane >> 4, ln = lane & 15;
    const int wr = w >> 1, wc = w & 1;

    const int NXB = (MODE == 1) ? 18 : 6;
    const int bx = blockIdx.x;
    const int xcd = bx & 7, slot = bx >> 3;
    const int n0 = (slot % NXB) * 128;
    const int m0 = ((slot / NXB) * 8 + xcd) * 128;

    const int srow = lane >> 3;
    const int ssw = ((lane & 7) ^ srow) * 8;
    const unsigned short* agp[4];
    const unsigned short* bgp[4];
    void* asl[4];
    void* bsl[4];
#pragma unroll
    for (int i = 0; i < 4; ++i) {
        const int R = i * 32 + w * 8;
        agp[i] = A + (size_t)(m0 + R + srow) * CC + ssw;
        bgp[i] = Bw + (size_t)(n0 + R + srow) * CC + ssw;
        asl[i] = &As[R][0];
        bsl[i] = &Bs[R][0];
    }

    floatx4 acc[4][4];
#pragma unroll
    for (int mi = 0; mi < 4; ++mi)
#pragma unroll
        for (int ni = 0; ni < 4; ++ni) acc[mi][ni] = (floatx4){0.f, 0.f, 0.f, 0.f};

    const int ps0 = (quad ^ (ln & 7)) * 8;

    for (int k0 = 0; k0 < CC; k0 += 64) {
        __syncthreads();
#pragma unroll
        for (int i = 0; i < 4; ++i) {
            gl_lds16(agp[i] + k0, asl[i]);
            gl_lds16(bgp[i] + k0, bsl[i]);
        }
        __syncthreads();
#pragma unroll
        for (int kh = 0; kh < 2; ++kh) {
            const int ps = ps0 ^ (kh * 32);
            short8 af[4], bfr[4];
#pragma unroll
            for (int mi = 0; mi < 4; ++mi)
                af[mi] = *(const short8*)&As[wr * 64 + mi * 16 + ln][ps];
#pragma unroll
            for (int ni = 0; ni < 4; ++ni)
                bfr[ni] = *(const short8*)&Bs[wc * 64 + ni * 16 + ln][ps];
#pragma unroll
            for (int mi = 0; mi < 4; ++mi)
#pragma unroll
                for (int ni = 0; ni < 4; ++ni)
                    acc[mi][ni] = __builtin_amdgcn_mfma_f32_16x16x32_bf16(af[mi], bfr[ni], acc[mi][ni], 0, 0, 0);
        }
    }

    if (MODE == 0) {
        float* outf = (float*)out0;
        float bv[4];
#pragma unroll
        for (int ni = 0; ni < 4; ++ni) bv[ni] = b0p[n0 + wc * 64 + ni * 16 + ln];
#pragma unroll
        for (int mi = 0; mi < 4; ++mi)
#pragma unroll
            for (int r = 0; r < 4; ++r) {
                size_t row = m0 + wr * 64 + mi * 16 + quad * 4 + r;
#pragma unroll
                for (int ni = 0; ni < 4; ++ni)
                    outf[row * CC + n0 + wc * 64 + ni * 16 + ln] = acc[mi][ni][r] + bv[ni];
            }
    } else {
        const int seg = n0 / CC;
        const int nl0 = n0 - seg * CC;
        const float* bp = (seg == 0) ? b0p : (seg == 1) ? b1p : b2p;
        float bv[4];
#pragma unroll
        for (int ni = 0; ni < 4; ++ni) bv[ni] = bp[nl0 + wc * 64 + ni * 16 + ln];

        if (seg < 2) {
            unsigned short* outb = (unsigned short*)(seg == 0 ? out0 : out1);
#pragma unroll
            for (int mi = 0; mi < 4; ++mi)
#pragma unroll
                for (int r = 0; r < 4; ++r) {
                    size_t row = m0 + wr * 64 + mi * 16 + quad * 4 + r;
#pragma unroll
                    for (int ni = 0; ni < 4; ++ni)
                        outb[row * CC + nl0 + wc * 64 + ni * 16 + ln] = f2bf(acc[mi][ni][r] + bv[ni]);
                }
        } else {
            unsigned short* outb = (unsigned short*)out2;
            const int b = m0 >> 11;
#pragma unroll
            for (int ni = 0; ni < 4; ++ni) {
                int col = nl0 + wc * 64 + ni * 16 + ln;
                int h = col / HD, d = col % HD;
                size_t base = (size_t)((b * NHD + h) * HD + d) * TT;
#pragma unroll
                for (int mi = 0; mi < 4; ++mi) {
                    int t = (m0 & 2047) + wr * 64 + mi * 16 + quad * 4;
                    ushort4 pk;
                    pk.x = f2bf(acc[mi][ni][0] + bv[ni]);
                    pk.y = f2bf(acc[mi][ni][1] + bv[ni]);
                    pk.z = f2bf(acc[mi][ni][2] + bv[ni]);
                    pk.w = f2bf(acc[mi][ni][3] + bv[ni]);
                    *(ushort4*)(outb + base + t) = pk;
                }
            }
        }
    }
}

// RoPE in-place via precomputed table, vectorized: each thread handles 8
// rotary pairs (short8 loads/stores). q pre-scaled by (1/sqrt(48))*log2(e).
__global__ __launch_bounds__(256) void rope_bf(unsigned short* __restrict__ q,
                                               unsigned short* __restrict__ k,
                                               const float2* __restrict__ tab) {
    int idx = blockIdx.x * blockDim.x + threadIdx.x;  // over B*T*H*3
    const int HALF = HD / 2;
    int p8 = idx % 3;          // which group of 8 pairs
    int rest = idx / 3;
    int h = rest % NHD;
    int n = rest / NHD;        // b*T + t
    int t = n & (TT - 1);
    const float QSC = 0.14433756729740643f * 1.4426950408889634f;
    size_t base = (size_t)n * CC + h * HD + p8 * 8;
    const float2* tp = tab + t * HALF + p8 * 8;

    short8 q1 = *(const short8*)(q + base);
    short8 q2 = *(const short8*)(q + base + HALF);
    short8 k1 = *(const short8*)(k + base);
    short8 k2 = *(const short8*)(k + base + HALF);
    short8 r1, r2, s1, s2;
#pragma unroll
    for (int jj = 0; jj < 8; ++jj) {
        float2 cssn = tp[jj];
        float cs = cssn.x, sn = cssn.y;
        float a = bfu2f((unsigned short)q1[jj]), bb = bfu2f((unsigned short)q2[jj]);
        r1[jj] = (short)f2bf((a * cs - bb * sn) * QSC);
        r2[jj] = (short)f2bf((bb * cs + a * sn) * QSC);
        float c2 = bfu2f((unsigned short)k1[jj]), d2 = bfu2f((unsigned short)k2[jj]);
        s1[jj] = (short)f2bf(c2 * cs - d2 * sn);
        s2[jj] = (short)f2bf(d2 * cs + c2 * sn);
    }
    *(short8*)(q + base) = r1;
    *(short8*)(q + base + HALF) = r2;
    *(short8*)(k + base) = s1;
    *(short8*)(k + base + HALF) = s2;
}

// MFMA flash attention, exp2-domain, fixed softmax reference (m=0).
// LDS-traffic-minimized: only K (double-buffered, mask-column trick) and the
// P transpose buffer live in LDS; Q and V fragments come straight from global
// (L1/L2-resident; V addrs identical across the 4 waves, 32 blocks per (b,h)
// pinned to one XCD). One barrier per k-step (write next tile to other buf).
// launch_bounds (256,4): 128-VGPR cap -- round-1's (256,8) forced 64 and
// spilled everything to scratch (WRITE_SIZE 12->42 MB, 3.3x slowdown).
__global__ __launch_bounds__(256, 4) void attn_kernel(const unsigned short* __restrict__ qb,
                                                      const unsigned short* __restrict__ kb,
                                                      const unsigned short* __restrict__ vt,
                                                      const float* __restrict__ amask,
                                                      unsigned short* __restrict__ ctx) {
    const int bx = blockIdx.x;
    const int xcd = bx & 7;
    const int rem = bx >> 3;             // [0,256)
    const int u = rem & 31;              // zig-zag qt index
    const int qt = (u & 1) ? (31 - (u >> 1)) : (u >> 1);
    const int j = ((rem >> 5) << 3) | xcd;  // (b,h) group, grouped per XCD
    const int b = j >> 4, h = j & 15;
    const int tid = threadIdx.x;
    const int w = tid >> 6, lane = tid & 63;
    const int g = lane >> 4, ln = lane & 15;

    __shared__ __align__(16) unsigned short Ks[2][64][72];
    __shared__ __align__(16) unsigned short Pw[4][16][72];
    __shared__ __align__(16) float l_s[4][16];

    const short8 z8 = {0, 0, 0, 0, 0, 0, 0, 0};
    const short8 ones8 = {0x3F80, 0x3F80, 0x3F80, 0x3F80, 0x3F80, 0x3F80, 0x3F80, 0x3F80};

    // zero Ks pad columns 48..63 in BOTH buffers (col 48 rewritten per step)
    {
        int buf = tid >> 7, r = (tid >> 1) & 63, half = tid & 1;
        *(short8*)&Ks[buf][r][48 + half * 8] = z8;
    }

    const int ck1 = tid + 256;
    const int rK0 = tid / 6, sK0 = tid % 6;
    const int rK1 = ck1 / 6, sK1 = ck1 % 6;
    const unsigned short* kp0 = kb + (size_t)(b * TT + rK0) * CC + h * HD + sK0 * 8;
    const unsigned short* kp1 = kb + (size_t)(b * TT + rK1) * CC + h * HD + sK1 * 8;
    const float* mp = amask + b * TT + (tid & 63);
    const float MBS = -10000.0f * 1.4426950408889634f;

    // V direct-load pointers: d-row = n*16+ln, col offset g*8, advance 64/step
    const unsigned short* vp0 = vt + ((size_t)((b * NHD + h) * HD) + 0 * 16 + ln) * TT + g * 8;
    const unsigned short* vp1 = vt + ((size_t)((b * NHD + h) * HD) + 1 * 16 + ln) * TT + g * 8;
    const unsigned short* vp2 = vt + ((size_t)((b * NHD + h) * HD) + 2 * 16 + ln) * TT + g * 8;
    const short8 vone = (ln == 0) ? ones8 : z8;  // ones-row fragment (l accumulator)

    const int q0 = qt * 64;

    // Q fragments: straight from global into registers; mask column (48) is
    // a constant {1.0, 0...} fragment on the g==2 quad.
    const unsigned short* qrow = qb + (size_t)(b * TT + q0 + w * 16 + ln) * CC + h * HD;
    short8 aq0 = *(const short8*)(qrow + g * 8);
    short8 aq1;
    if (g < 2) {
        aq1 = *(const short8*)(qrow + 32 + g * 8);
    } else {
        aq1 = z8;
        if (g == 2) aq1[0] = (short)0x3F80;
    }

    // prologue: tile 0 -> regs -> Ks[0]
    short8 kr0, kr1;
    float mr = 1.0f;
    kr0 = *(const short8*)kp0;
    if (tid < 128) kr1 = *(const short8*)kp1;
    if (tid < 64) mr = *mp;
    *(short8*)&Ks[0][rK0][sK0 * 8] = kr0;
    if (tid < 128) *(short8*)&Ks[0][rK1][sK1 * 8] = kr1;
    if (tid < 64) Ks[0][tid][48] = f2bf((1.0f - mr) * MBS);
    __syncthreads();

    const int q_lane = q0 + w * 16 + ln;
    floatx4 o0 = {0.f, 0.f, 0.f, 0.f}, o1 = o0, o2 = o0, o3 = o0;

    for (int kt = 0; kt <= qt; ++kt) {
        const int buf = kt & 1;
        // issue next-tile global loads early; latency hides under compute
        if (kt < qt) {
            kp0 += (size_t)64 * CC; kr0 = *(const short8*)kp0;
            if (tid < 128) { kp1 += (size_t)64 * CC; kr1 = *(const short8*)kp1; }
            if (tid < 64) { mp += 64; mr = *mp; }
        }

        const int k0 = kt * 64;
        floatx4 sc[4];
#pragma unroll
        for (int c = 0; c < 4; ++c) {
            short8 kf0 = *(const short8*)&Ks[buf][c * 16 + ln][g * 8];
            short8 kf1 = *(const short8*)&Ks[buf][c * 16 + ln][32 + g * 8];
            floatx4 z = {0.f, 0.f, 0.f, 0.f};
            z = __builtin_amdgcn_mfma_f32_16x16x32_bf16(kf0, aq0, z, 0, 0, 0);
            z = __builtin_amdgcn_mfma_f32_16x16x32_bf16(kf1, aq1, z, 0, 0, 0);
            sc[c] = z;
        }

        const bool diag = (kt == qt);
#pragma unroll
        for (int c = 0; c < 4; ++c) {
            float pv[4];
#pragma unroll
            for (int r = 0; r < 4; ++r) {
                float e = __builtin_amdgcn_exp2f(sc[c][r]);
                if (diag && (k0 + c * 16 + g * 4 + r > q_lane)) e = 0.f;
                pv[r] = e;
            }
            uint2 pk;
            pk.x = pk_bf2(pv[0], pv[1]);
            pk.y = pk_bf2(pv[2], pv[3]);
            *(uint2*)&Pw[w][ln][c * 16 + g * 4] = pk;
        }

        // V fragments direct from global (L1-hot: same addrs across 4 waves);
        // issued between Pw write and read so L1 latency overlaps the
        // lgkm turnaround.
        short8 v00 = *(const short8*)vp0;
        short8 v01 = *(const short8*)(vp0 + 32);
        short8 v10 = *(const short8*)vp1;
        short8 v11 = *(const short8*)(vp1 + 32);
        short8 v20 = *(const short8*)vp2;
        short8 v21 = *(const short8*)(vp2 + 32);
        vp0 += 64; vp1 += 64; vp2 += 64;

        short8 pa0 = *(const short8*)&Pw[w][ln][g * 8];
        short8 pa1 = *(const short8*)&Pw[w][ln][32 + g * 8];

        o0 = __builtin_amdgcn_mfma_f32_16x16x32_bf16(pa0, v00, o0, 0, 0, 0);
        o0 = __builtin_amdgcn_mfma_f32_16x16x32_bf16(pa1, v01, o0, 0, 0, 0);
        o1 = __builtin_amdgcn_mfma_f32_16x16x32_bf16(pa0, v10, o1, 0, 0, 0);
        o1 = __builtin_amdgcn_mfma_f32_16x16x32_bf16(pa1, v11, o1, 0, 0, 0);
        o2 = __builtin_amdgcn_mfma_f32_16x16x32_bf16(pa0, v20, o2, 0, 0, 0);
        o2 = __builtin_amdgcn_mfma_f32_16x16x32_bf16(pa1, v21, o2, 0, 0, 0);
        o3 = __builtin_amdgcn_mfma_f32_16x16x32_bf16(pa0, vone, o3, 0, 0, 0);
        o3 = __builtin_amdgcn_mfma_f32_16x16x32_bf16(pa1, vone, o3, 0, 0, 0);

        // write prefetched tile kt+1 into the other buffer, then single barrier
        if (kt < qt) {
            *(short8*)&Ks[buf ^ 1][rK0][sK0 * 8] = kr0;
            if (tid < 128) *(short8*)&Ks[buf ^ 1][rK1][sK1 * 8] = kr1;
            if (tid < 64) Ks[buf ^ 1][tid][48] = f2bf((1.0f - mr) * MBS);
        }
        __syncthreads();
    }

    if (ln == 0) *(floatx4*)&l_s[w][g * 4] = o3;   // per-wave LDS, no barrier
    floatx4 l4 = *(const floatx4*)&l_s[w][g * 4];
#pragma unroll
    for (int r = 0; r < 4; ++r) {
        float inv_l = 1.0f / l4[r];
        int t = q0 + w * 16 + g * 4 + r;
        unsigned short* dst = ctx + (size_t)(b * TT + t) * CC + h * HD;
        dst[ln] = f2bf(o0[r] * inv_l);
        dst[16 + ln] = f2bf(o1[r] * inv_l);
        dst[32 + ln] = f2bf(o2[r] * inv_l);
    }
}

extern "C" void kernel_launch(void* const* d_in, const int* in_sizes, int n_in,
                              void* d_out, int out_size, void* d_ws, size_t ws_size,
                              hipStream_t stream) {
    const float* hs = (const float*)d_in[0];
    const float* amask = (const float*)d_in[1];
    const float* Wq = (const float*)d_in[2];
    const float* bq = (const float*)d_in[3];
    const float* Wk = (const float*)d_in[4];
    const float* bk = (const float*)d_in[5];
    const float* Wv = (const float*)d_in[6];
    const float* bv = (const float*)d_in[7];
    const float* Wo = (const float*)d_in[8];
    const float* bo = (const float*)d_in[9];

    const size_t NELEM = (size_t)BB * TT * CC;  // 6291456
    const size_t WELEM = (size_t)CC * CC;       // 589824
    unsigned short* hb  = (unsigned short*)d_ws;
    unsigned short* qbuf = hb + NELEM;
    unsigned short* kbuf = qbuf + NELEM;
    unsigned short* vtb = kbuf + NELEM;   // bf16 [B,H,D,T]
    unsigned short* ctxb = vtb + NELEM;
    unsigned short* wqb = ctxb + NELEM;   // wq/wk/wv contiguous = stacked [2304][768]
    unsigned short* wkb = wqb + WELEM;
    unsigned short* wvb = wkb + WELEM;
    unsigned short* wob = wvb + WELEM;
    float2* ropetab = (float2*)(wob + WELEM);  // [2048][24]

    cast_hs<<<NELEM / 1024, 256, 0, stream>>>(hs, hb);
    dim3 wgrid(WELEM / 1024, 4);
    cast_w4<<<wgrid, 256, 0, stream>>>(Wq, Wk, Wv, Wo, wqb, wkb, wvb, wob);
    rope_table<<<(TT * (HD / 2)) / 256, 256, 0, stream>>>(ropetab);

    gemm_mfma<1><<<18 * 64, 256, 0, stream>>>(hb, wqb, bq, bk, bv, qbuf, kbuf, vtb);

    int rope_total = BB * TT * NHD * 3;  // 8 pairs per thread
    rope_bf<<<rope_total / 256, 256, 0, stream>>>(qbuf, kbuf, ropetab);

    attn_kernel<<<2048, 256, 0, stream>>>(qbuf, kbuf, vtb, amask, ctxb);

    gemm_mfma<0><<<6 * 64, 256, 0, stream>>>(ctxb, wob, bo, nullptr, nullptr,
                                             (float*)d_out, nullptr, nullptr);
}

// Round 3
// 283.925 us; speedup vs baseline: 1.3886x; 1.2109x over previous
//
#include <hip/hip_runtime.h>
#include <hip/hip_bf16.h>
#include <math.h>

#define BB 4
#define TT 2048
#define CC 768
#define NHD 16
#define HD 48
#define NQT 32  // TT/64

typedef __hip_bfloat16 bf16;
typedef __attribute__((ext_vector_type(8))) short short8;
typedef __attribute__((ext_vector_type(4))) float floatx4;

__device__ __forceinline__ unsigned short f2bf(float x) {
    bf16 h = __float2bfloat16(x);
    return *(unsigned short*)&h;
}
__device__ __forceinline__ float bfu2f(unsigned short u) {
    return __uint_as_float(((unsigned)u) << 16);
}

// async global->LDS, 16B per lane; LDS dest = wave-uniform base + lane*16
__device__ __forceinline__ void gl_lds16(const void* g, void* s) {
    __builtin_amdgcn_global_load_lds((const __attribute__((address_space(1))) void*)g,
                                     (__attribute__((address_space(3))) void*)s, 16, 0, 0);
}

// pack two fp32 -> packed bf16 pair (round-half-up; inputs are probabilities >= 0)
__device__ __forceinline__ unsigned int pk_bf2(float a, float b) {
    unsigned int ua = __float_as_uint(a) + 0x8000u;
    unsigned int ub = __float_as_uint(b) + 0x8000u;
    return __builtin_amdgcn_perm(ub, ua, 0x07060302);
}

// hot-loop barrier: make LDS writes visible, do NOT drain vmcnt -- register
// global loads (K/V prefetch) stay in flight across the barrier.
#define HOT_BARRIER() asm volatile("s_waitcnt lgkmcnt(0)\n\ts_barrier" ::: "memory")

// ---------- fp32 -> bf16 casts ----------
__global__ __launch_bounds__(256) void cast_hs(const float* __restrict__ src,
                                               unsigned short* __restrict__ dst) {
    int i = (blockIdx.x * 256 + threadIdx.x) * 4;
    float4 v = *(const float4*)(src + i);
    ushort4 p;
    p.x = f2bf(v.x); p.y = f2bf(v.y); p.z = f2bf(v.z); p.w = f2bf(v.w);
    *(ushort4*)(dst + i) = p;
}

__global__ __launch_bounds__(256) void cast_w4(const float* __restrict__ s0, const float* __restrict__ s1,
                                               const float* __restrict__ s2, const float* __restrict__ s3,
                                               unsigned short* __restrict__ d0, unsigned short* __restrict__ d1,
                                               unsigned short* __restrict__ d2, unsigned short* __restrict__ d3) {
    const float* s; unsigned short* d;
    switch (blockIdx.y) {
        case 0: s = s0; d = d0; break;
        case 1: s = s1; d = d1; break;
        case 2: s = s2; d = d2; break;
        default: s = s3; d = d3; break;
    }
    int i = (blockIdx.x * 256 + threadIdx.x) * 4;
    float4 v = *(const float4*)(s + i);
    ushort4 p;
    p.x = f2bf(v.x); p.y = f2bf(v.y); p.z = f2bf(v.z); p.w = f2bf(v.w);
    *(ushort4*)(d + i) = p;
}

// ---------- RoPE sincos table: tab[t][p] = {cos, sin}, p in [0,24) ----------
__global__ __launch_bounds__(256) void rope_table(float2* __restrict__ tab) {
    int idx = blockIdx.x * 256 + threadIdx.x;  // over 2048*24
    int t = idx / 24, p = idx % 24;
    float inv_freq = powf(10000.0f, -((float)(2 * p) / (float)HD));
    float ang = (float)t * inv_freq;
    float sn, cs;
    sincosf(ang, &sn, &cs);
    tab[idx] = make_float2(cs, sn);
}

// ---------- bf16 MFMA NT-GEMM, BK=64, lds-direct staging with XOR-swizzle ----------
// 1-D grid, XCD-swizzled: bx -> (xcd = bx&7, slot = bx>>3); x = slot % NXB,
// y = (slot/NXB)*8 + xcd  => all blocks sharing an A row-band (same y) land on
// one XCD so the A-tile is fetched once per XCD-L2, not 8x.
// MODE 0: N=768 (NXB=6), fp32 row-major out. MODE 1: fused QKV N=2304 (NXB=18).
template <int MODE>
__global__ __launch_bounds__(256) void gemm_mfma(const unsigned short* __restrict__ A,
                                                 const unsigned short* __restrict__ Bw,
                                                 const float* __restrict__ b0p,
                                                 const float* __restrict__ b1p,
                                                 const float* __restrict__ b2p,
                                                 void* __restrict__ out0,
                                                 void* __restrict__ out1,
                                                 void* __restrict__ out2) {
    __shared__ __align__(16) unsigned short As[128][64];
    __shared__ __align__(16) unsigned short Bs[128][64];
    const int tid = threadIdx.x;
    const int w = tid >> 6, lane = tid & 63;
    const int quad = lane >> 4, ln = lane & 15;
    const int wr = w >> 1, wc = w & 1;

    const int NXB = (MODE == 1) ? 18 : 6;
    const int bx = blockIdx.x;
    const int xcd = bx & 7, slot = bx >> 3;
    const int n0 = (slot % NXB) * 128;
    const int m0 = ((slot / NXB) * 8 + xcd) * 128;

    const int srow = lane >> 3;
    const int ssw = ((lane & 7) ^ srow) * 8;
    const unsigned short* agp[4];
    const unsigned short* bgp[4];
    void* asl[4];
    void* bsl[4];
#pragma unroll
    for (int i = 0; i < 4; ++i) {
        const int R = i * 32 + w * 8;
        agp[i] = A + (size_t)(m0 + R + srow) * CC + ssw;
        bgp[i] = Bw + (size_t)(n0 + R + srow) * CC + ssw;
        asl[i] = &As[R][0];
        bsl[i] = &Bs[R][0];
    }

    floatx4 acc[4][4];
#pragma unroll
    for (int mi = 0; mi < 4; ++mi)
#pragma unroll
        for (int ni = 0; ni < 4; ++ni) acc[mi][ni] = (floatx4){0.f, 0.f, 0.f, 0.f};

    const int ps0 = (quad ^ (ln & 7)) * 8;

    for (int k0 = 0; k0 < CC; k0 += 64) {
        __syncthreads();
#pragma unroll
        for (int i = 0; i < 4; ++i) {
            gl_lds16(agp[i] + k0, asl[i]);
            gl_lds16(bgp[i] + k0, bsl[i]);
        }
        __syncthreads();
#pragma unroll
        for (int kh = 0; kh < 2; ++kh) {
            const int ps = ps0 ^ (kh * 32);
            short8 af[4], bfr[4];
#pragma unroll
            for (int mi = 0; mi < 4; ++mi)
                af[mi] = *(const short8*)&As[wr * 64 + mi * 16 + ln][ps];
#pragma unroll
            for (int ni = 0; ni < 4; ++ni)
                bfr[ni] = *(const short8*)&Bs[wc * 64 + ni * 16 + ln][ps];
#pragma unroll
            for (int mi = 0; mi < 4; ++mi)
#pragma unroll
                for (int ni = 0; ni < 4; ++ni)
                    acc[mi][ni] = __builtin_amdgcn_mfma_f32_16x16x32_bf16(af[mi], bfr[ni], acc[mi][ni], 0, 0, 0);
        }
    }

    if (MODE == 0) {
        float* outf = (float*)out0;
        float bv[4];
#pragma unroll
        for (int ni = 0; ni < 4; ++ni) bv[ni] = b0p[n0 + wc * 64 + ni * 16 + ln];
#pragma unroll
        for (int mi = 0; mi < 4; ++mi)
#pragma unroll
            for (int r = 0; r < 4; ++r) {
                size_t row = m0 + wr * 64 + mi * 16 + quad * 4 + r;
#pragma unroll
                for (int ni = 0; ni < 4; ++ni)
                    outf[row * CC + n0 + wc * 64 + ni * 16 + ln] = acc[mi][ni][r] + bv[ni];
            }
    } else {
        const int seg = n0 / CC;
        const int nl0 = n0 - seg * CC;
        const float* bp = (seg == 0) ? b0p : (seg == 1) ? b1p : b2p;
        float bv[4];
#pragma unroll
        for (int ni = 0; ni < 4; ++ni) bv[ni] = bp[nl0 + wc * 64 + ni * 16 + ln];

        if (seg < 2) {
            unsigned short* outb = (unsigned short*)(seg == 0 ? out0 : out1);
#pragma unroll
            for (int mi = 0; mi < 4; ++mi)
#pragma unroll
                for (int r = 0; r < 4; ++r) {
                    size_t row = m0 + wr * 64 + mi * 16 + quad * 4 + r;
#pragma unroll
                    for (int ni = 0; ni < 4; ++ni)
                        outb[row * CC + nl0 + wc * 64 + ni * 16 + ln] = f2bf(acc[mi][ni][r] + bv[ni]);
                }
        } else {
            unsigned short* outb = (unsigned short*)out2;
            const int b = m0 >> 11;
#pragma unroll
            for (int ni = 0; ni < 4; ++ni) {
                int col = nl0 + wc * 64 + ni * 16 + ln;
                int h = col / HD, d = col % HD;
                size_t base = (size_t)((b * NHD + h) * HD + d) * TT;
#pragma unroll
                for (int mi = 0; mi < 4; ++mi) {
                    int t = (m0 & 2047) + wr * 64 + mi * 16 + quad * 4;
                    ushort4 pk;
                    pk.x = f2bf(acc[mi][ni][0] + bv[ni]);
                    pk.y = f2bf(acc[mi][ni][1] + bv[ni]);
                    pk.z = f2bf(acc[mi][ni][2] + bv[ni]);
                    pk.w = f2bf(acc[mi][ni][3] + bv[ni]);
                    *(ushort4*)(outb + base + t) = pk;
                }
            }
        }
    }
}

// RoPE in-place via precomputed table, vectorized: each thread handles 8
// rotary pairs (short8 loads/stores). q pre-scaled by (1/sqrt(48))*log2(e).
__global__ __launch_bounds__(256) void rope_bf(unsigned short* __restrict__ q,
                                               unsigned short* __restrict__ k,
                                               const float2* __restrict__ tab) {
    int idx = blockIdx.x * blockDim.x + threadIdx.x;  // over B*T*H*3
    const int HALF = HD / 2;
    int p8 = idx % 3;          // which group of 8 pairs
    int rest = idx / 3;
    int h = rest % NHD;
    int n = rest / NHD;        // b*T + t
    int t = n & (TT - 1);
    const float QSC = 0.14433756729740643f * 1.4426950408889634f;
    size_t base = (size_t)n * CC + h * HD + p8 * 8;
    const float2* tp = tab + t * HALF + p8 * 8;

    short8 q1 = *(const short8*)(q + base);
    short8 q2 = *(const short8*)(q + base + HALF);
    short8 k1 = *(const short8*)(k + base);
    short8 k2 = *(const short8*)(k + base + HALF);
    short8 r1, r2, s1, s2;
#pragma unroll
    for (int jj = 0; jj < 8; ++jj) {
        float2 cssn = tp[jj];
        float cs = cssn.x, sn = cssn.y;
        float a = bfu2f((unsigned short)q1[jj]), bb = bfu2f((unsigned short)q2[jj]);
        r1[jj] = (short)f2bf((a * cs - bb * sn) * QSC);
        r2[jj] = (short)f2bf((bb * cs + a * sn) * QSC);
        float c2 = bfu2f((unsigned short)k1[jj]), d2 = bfu2f((unsigned short)k2[jj]);
        s1[jj] = (short)f2bf(c2 * cs - d2 * sn);
        s2[jj] = (short)f2bf(d2 * cs + c2 * sn);
    }
    *(short8*)(q + base) = r1;
    *(short8*)(q + base + HALF) = r2;
    *(short8*)(k + base) = s1;
    *(short8*)(k + base + HALF) = s2;
}

// MFMA flash attention, exp2-domain, fixed softmax reference (m=0).
// Structure (round 3):
//  - grid 1024, balanced pair schedule: each block does q-tiles {pair, 31-pair}
//    = exactly 33 k-steps -> no tail imbalance.
//  - K double-buffered in LDS (XOR-swizzled [2][64][64], mask col in unit 6),
//    register-prefetched one step ahead; ONE barrier per step.
//  - Q and V straight from global to registers; V prefetched one full
//    iteration ahead (consume-then-reload), so the FIFO vmcnt order is
//    [V(kt), K(kt+1)]: PV waits vmcnt(3), stage waits vmcnt(6) -- every load
//    gets ~a full iteration of hiding (counted waits, compiler-inserted).
//  - hot-loop barrier is raw `s_waitcnt lgkmcnt(0); s_barrier` so register
//    loads are NOT drained at the barrier (__syncthreads may drain vmcnt).
//  - Pw transpose buffer XOR-swizzled [4][16][64].
__global__ __launch_bounds__(256, 4) void attn_kernel(const unsigned short* __restrict__ qb,
                                                      const unsigned short* __restrict__ kb,
                                                      const unsigned short* __restrict__ vt,
                                                      const float* __restrict__ amask,
                                                      unsigned short* __restrict__ ctx) {
    const int bx = blockIdx.x;
    const int xcd = bx & 7;
    const int rem = bx >> 3;                // [0,128)
    const int pair = rem & 15;
    const int j = ((rem >> 4) << 3) | xcd;  // (b,h) group, grouped per XCD
    const int b = j >> 4, h = j & 15;
    const int tid = threadIdx.x;
    const int w = tid >> 6, lane = tid & 63;
    const int g = lane >> 4, ln = lane & 15;
    const int sw = ln & 7;

    __shared__ __align__(16) unsigned short Ks[2][64][64];
    __shared__ __align__(16) unsigned short Pw[4][16][64];
    __shared__ __align__(16) float l_s[4][16];

    const short8 z8 = {0, 0, 0, 0, 0, 0, 0, 0};
    const short8 ones8 = {0x3F80, 0x3F80, 0x3F80, 0x3F80, 0x3F80, 0x3F80, 0x3F80, 0x3F80};

    // zero pad units 6,7 (XOR-swizzled) in both buffers, once.
    // unit 6 elem 0 = mask slot (rewritten per step); elems 49..63 stay 0.
    {
        int buf = tid >> 7, rr = (tid >> 1) & 63, half = tid & 1;
        *(short8*)&Ks[buf][rr][((6 + half) ^ (rr & 7)) * 8] = z8;
    }

    const int ck1 = tid + 256;
    const int rK0 = tid / 6, sK0 = tid % 6;
    const int rK1 = ck1 / 6, sK1 = ck1 % 6;
    const int swK0 = (sK0 ^ (rK0 & 7)) * 8;   // swizzled col for K stage
    const int swK1 = (sK1 ^ (rK1 & 7)) * 8;
    const unsigned short* kbase0 = kb + (size_t)(b * TT + rK0) * CC + h * HD + sK0 * 8;
    const unsigned short* kbase1 = kb + (size_t)(b * TT + rK1) * CC + h * HD + sK1 * 8;
    const float* mbase = amask + b * TT + (tid & 63);
    const float MBS = -10000.0f * 1.4426950408889634f;
    const int mcol = (6 ^ (lane & 7)) * 8;    // swizzled mask-element col (row=lane)

    // V direct-load bases: d-row = n*16+ln, col offset g*8, advance 64/step
    const unsigned short* vbase0 = vt + ((size_t)((b * NHD + h) * HD) + ln) * TT + g * 8;
    const unsigned short* vbase1 = vbase0 + (size_t)16 * TT;
    const unsigned short* vbase2 = vbase0 + (size_t)32 * TT;
    const short8 vone = (ln == 0) ? ones8 : z8;  // ones-row fragment (l accumulator)

    for (int rep = 0; rep < 2; ++rep) {
        const int qt = rep ? (NQT - 1 - pair) : pair;
        const int q0 = qt * 64;

        // Q fragments straight from global; mask column (48) pairs with a
        // constant {1.0,0...} element on the g==2 quad of aq1.
        const unsigned short* qrow = qb + (size_t)(b * TT + q0 + w * 16 + ln) * CC + h * HD;
        short8 aq0 = *(const short8*)(qrow + g * 8);
        short8 aq1;
        if (g < 2) {
            aq1 = *(const short8*)(qrow + 32 + g * 8);
        } else {
            aq1 = z8;
            if (g == 2) aq1[0] = (short)0x3F80;
        }

        const unsigned short* kp0 = kbase0;
        const unsigned short* kp1 = kbase1;
        const float* mp = mbase;
        const unsigned short* vp0 = vbase0;
        const unsigned short* vp1 = vbase1;
        const unsigned short* vp2 = vbase2;

        // prologue: K(0), mask(0), V(0) into registers
        short8 kr0, kr1;
        float mr = 1.0f;
        kr0 = *(const short8*)kp0;
        if (tid < 128) kr1 = *(const short8*)kp1;
        if (tid < 64) mr = *mp;
        short8 vc00 = *(const short8*)vp0;
        short8 vc01 = *(const short8*)(vp0 + 32);
        short8 vc10 = *(const short8*)vp1;
        short8 vc11 = *(const short8*)(vp1 + 32);
        short8 vc20 = *(const short8*)vp2;
        short8 vc21 = *(const short8*)(vp2 + 32);

        __syncthreads();   // previous rep's last reads of Ks done
        *(short8*)&Ks[0][rK0][swK0] = kr0;
        if (tid < 128) *(short8*)&Ks[0][rK1][swK1] = kr1;
        if (tid < 64) Ks[0][lane][mcol] = f2bf((1.0f - mr) * MBS);
        __syncthreads();

        const int q_lane = q0 + w * 16 + ln;
        floatx4 o0 = {0.f, 0.f, 0.f, 0.f}, o1 = o0, o2 = o0, o3 = o0;

        for (int kt = 0; kt <= qt; ++kt) {
            const int buf = kt & 1;
            // K prefetch for tile kt+1 (consumed at bottom of this iteration)
            if (kt < qt) {
                kp0 += (size_t)64 * CC; kr0 = *(const short8*)kp0;
                if (tid < 128) { kp1 += (size_t)64 * CC; kr1 = *(const short8*)kp1; }
                if (tid < 64) { mp += 64; mr = *mp; }
            }

            const int k0 = kt * 64;
            floatx4 sc[4];
#pragma unroll
            for (int c = 0; c < 4; ++c) {
                short8 kf0 = *(const short8*)&Ks[buf][c * 16 + ln][(g ^ sw) * 8];
                short8 kf1 = *(const short8*)&Ks[buf][c * 16 + ln][((4 + g) ^ sw) * 8];
                floatx4 z = {0.f, 0.f, 0.f, 0.f};
                z = __builtin_amdgcn_mfma_f32_16x16x32_bf16(kf0, aq0, z, 0, 0, 0);
                z = __builtin_amdgcn_mfma_f32_16x16x32_bf16(kf1, aq1, z, 0, 0, 0);
                sc[c] = z;
            }

            const bool diag = (kt == qt);
#pragma unroll
            for (int c = 0; c < 4; ++c) {
                float pv[4];
#pragma unroll
                for (int r = 0; r < 4; ++r) {
                    float e = __builtin_amdgcn_exp2f(sc[c][r]);
                    if (diag && (k0 + c * 16 + g * 4 + r > q_lane)) e = 0.f;
                    pv[r] = e;
                }
                uint2 pk;
                pk.x = pk_bf2(pv[0], pv[1]);
                pk.y = pk_bf2(pv[2], pv[3]);
                // original elems c*16+g*4 -> unit 2c+(g>>1), swizzled by row (ln)
                *(uint2*)&Pw[w][ln][((2 * c + (g >> 1)) ^ sw) * 8 + (g & 1) * 4] = pk;
            }

            short8 pa0 = *(const short8*)&Pw[w][ln][(g ^ sw) * 8];
            short8 pa1 = *(const short8*)&Pw[w][ln][((4 + g) ^ sw) * 8];

            // PV consumes vc* (loaded one full iteration ago -> latency hidden)
            o0 = __builtin_amdgcn_mfma_f32_16x16x32_bf16(pa0, vc00, o0, 0, 0, 0);
            o0 = __builtin_amdgcn_mfma_f32_16x16x32_bf16(pa1, vc01, o0, 0, 0, 0);
            o1 = __builtin_amdgcn_mfma_f32_16x16x32_bf16(pa0, vc10, o1, 0, 0, 0);
            o1 = __builtin_amdgcn_mfma_f32_16x16x32_bf16(pa1, vc11, o1, 0, 0, 0);
            o2 = __builtin_amdgcn_mfma_f32_16x16x32_bf16(pa0, vc20, o2, 0, 0, 0);
            o2 = __builtin_amdgcn_mfma_f32_16x16x32_bf16(pa1, vc21, o2, 0, 0, 0);
            o3 = __builtin_amdgcn_mfma_f32_16x16x32_bf16(pa0, vone, o3, 0, 0, 0);
            o3 = __builtin_amdgcn_mfma_f32_16x16x32_bf16(pa1, vone, o3, 0, 0, 0);

            if (kt < qt) {
                // V prefetch for tile kt+1 (consumed next iteration)
                vp0 += 64; vp1 += 64; vp2 += 64;
                vc00 = *(const short8*)vp0; vc01 = *(const short8*)(vp0 + 32);
                vc10 = *(const short8*)vp1; vc11 = *(const short8*)(vp1 + 32);
                vc20 = *(const short8*)vp2; vc21 = *(const short8*)(vp2 + 32);

                // stage K(kt+1) into the other buffer (waits vmcnt(6): V in flight)
                *(short8*)&Ks[buf ^ 1][rK0][swK0] = kr0;
                if (tid < 128) *(short8*)&Ks[buf ^ 1][rK1][swK1] = kr1;
                if (tid < 64) Ks[buf ^ 1][lane][mcol] = f2bf((1.0f - mr) * MBS);
                HOT_BARRIER();
            }
        }

        if (ln == 0) *(floatx4*)&l_s[w][g * 4] = o3;   // per-wave LDS, no barrier
        floatx4 l4 = *(const floatx4*)&l_s[w][g * 4];
#pragma unroll
        for (int r = 0; r < 4; ++r) {
            float inv_l = 1.0f / l4[r];
            int t = q0 + w * 16 + g * 4 + r;
            unsigned short* dst = ctx + (size_t)(b * TT + t) * CC + h * HD;
            dst[ln] = f2bf(o0[r] * inv_l);
            dst[16 + ln] = f2bf(o1[r] * inv_l);
            dst[32 + ln] = f2bf(o2[r] * inv_l);
        }
    }
}

extern "C" void kernel_launch(void* const* d_in, const int* in_sizes, int n_in,
                              void* d_out, int out_size, void* d_ws, size_t ws_size,
                              hipStream_t stream) {
    const float* hs = (const float*)d_in[0];
    const float* amask = (const float*)d_in[1];
    const float* Wq = (const float*)d_in[2];
    const float* bq = (const float*)d_in[3];
    const float* Wk = (const float*)d_in[4];
    const float* bk = (const float*)d_in[5];
    const float* Wv = (const float*)d_in[6];
    const float* bv = (const float*)d_in[7];
    const float* Wo = (const float*)d_in[8];
    const float* bo = (const float*)d_in[9];

    const size_t NELEM = (size_t)BB * TT * CC;  // 6291456
    const size_t WELEM = (size_t)CC * CC;       // 589824
    unsigned short* hb  = (unsigned short*)d_ws;
    unsigned short* qbuf = hb + NELEM;
    unsigned short* kbuf = qbuf + NELEM;
    unsigned short* vtb = kbuf + NELEM;   // bf16 [B,H,D,T]
    unsigned short* ctxb = vtb + NELEM;
    unsigned short* wqb = ctxb + NELEM;   // wq/wk/wv contiguous = stacked [2304][768]
    unsigned short* wkb = wqb + WELEM;
    unsigned short* wvb = wkb + WELEM;
    unsigned short* wob = wvb + WELEM;
    float2* ropetab = (float2*)(wob + WELEM);  // [2048][24]

    cast_hs<<<NELEM / 1024, 256, 0, stream>>>(hs, hb);
    dim3 wgrid(WELEM / 1024, 4);
    cast_w4<<<wgrid, 256, 0, stream>>>(Wq, Wk, Wv, Wo, wqb, wkb, wvb, wob);
    rope_table<<<(TT * (HD / 2)) / 256, 256, 0, stream>>>(ropetab);

    gemm_mfma<1><<<18 * 64, 256, 0, stream>>>(hb, wqb, bq, bk, bv, qbuf, kbuf, vtb);

    int rope_total = BB * TT * NHD * 3;  // 8 pairs per thread
    rope_bf<<<rope_total / 256, 256, 0, stream>>>(qbuf, kbuf, ropetab);

    attn_kernel<<<1024, 256, 0, stream>>>(qbuf, kbuf, vtb, amask, ctxb);

    gemm_mfma<0><<<6 * 64, 256, 0, stream>>>(ctxb, wob, bo, nullptr, nullptr,
                                             (float*)d_out, nullptr, nullptr);
}

// Round 4
// 221.251 us; speedup vs baseline: 1.7819x; 1.2833x over previous
//
#include <hip/hip_runtime.h>
#include <hip/hip_bf16.h>
#include <math.h>

#define BB 4
#define TT 2048
#define CC 768
#define NHD 16
#define HD 48
#define NQT2 16  // TT/128

typedef __hip_bfloat16 bf16;
typedef __attribute__((ext_vector_type(8))) short short8;
typedef __attribute__((ext_vector_type(4))) float floatx4;

__device__ __forceinline__ unsigned short f2bf(float x) {
    bf16 h = __float2bfloat16(x);
    return *(unsigned short*)&h;
}
__device__ __forceinline__ float bfu2f(unsigned short u) {
    return __uint_as_float(((unsigned)u) << 16);
}

// async global->LDS, 16B per lane; LDS dest = wave-uniform base + lane*16
__device__ __forceinline__ void gl_lds16(const void* g, void* s) {
    __builtin_amdgcn_global_load_lds((const __attribute__((address_space(1))) void*)g,
                                     (__attribute__((address_space(3))) void*)s, 16, 0, 0);
}

// pack two fp32 -> packed bf16 pair (round-half-up; inputs are probabilities >= 0)
__device__ __forceinline__ unsigned int pk_bf2(float a, float b) {
    unsigned int ua = __float_as_uint(a) + 0x8000u;
    unsigned int ub = __float_as_uint(b) + 0x8000u;
    return __builtin_amdgcn_perm(ub, ua, 0x07060302);
}

// hot-loop barrier: make LDS writes visible, do NOT drain vmcnt -- register
// global loads (K/V prefetch) stay in flight across the barrier.
#define HOT_BARRIER() asm volatile("s_waitcnt lgkmcnt(0)\n\ts_barrier" ::: "memory")

// ---------- fp32 -> bf16 casts ----------
__global__ __launch_bounds__(256) void cast_hs(const float* __restrict__ src,
                                               unsigned short* __restrict__ dst) {
    int i = (blockIdx.x * 256 + threadIdx.x) * 4;
    float4 v = *(const float4*)(src + i);
    ushort4 p;
    p.x = f2bf(v.x); p.y = f2bf(v.y); p.z = f2bf(v.z); p.w = f2bf(v.w);
    *(ushort4*)(dst + i) = p;
}

__global__ __launch_bounds__(256) void cast_w4(const float* __restrict__ s0, const float* __restrict__ s1,
                                               const float* __restrict__ s2, const float* __restrict__ s3,
                                               unsigned short* __restrict__ d0, unsigned short* __restrict__ d1,
                                               unsigned short* __restrict__ d2, unsigned short* __restrict__ d3) {
    const float* s; unsigned short* d;
    switch (blockIdx.y) {
        case 0: s = s0; d = d0; break;
        case 1: s = s1; d = d1; break;
        case 2: s = s2; d = d2; break;
        default: s = s3; d = d3; break;
    }
    int i = (blockIdx.x * 256 + threadIdx.x) * 4;
    float4 v = *(const float4*)(s + i);
    ushort4 p;
    p.x = f2bf(v.x); p.y = f2bf(v.y); p.z = f2bf(v.z); p.w = f2bf(v.w);
    *(ushort4*)(d + i) = p;
}

// ---------- RoPE sincos table: tab[t][p] = {cos, sin}, p in [0,24) ----------
__global__ __launch_bounds__(256) void rope_table(float2* __restrict__ tab) {
    int idx = blockIdx.x * 256 + threadIdx.x;  // over 2048*24
    int t = idx / 24, p = idx % 24;
    float inv_freq = powf(10000.0f, -((float)(2 * p) / (float)HD));
    float ang = (float)t * inv_freq;
    float sn, cs;
    sincosf(ang, &sn, &cs);
    tab[idx] = make_float2(cs, sn);
}

// ---------- bf16 MFMA NT-GEMM, BK=64, lds-direct staging with XOR-swizzle ----------
template <int MODE>
__global__ __launch_bounds__(256) void gemm_mfma(const unsigned short* __restrict__ A,
                                                 const unsigned short* __restrict__ Bw,
                                                 const float* __restrict__ b0p,
                                                 const float* __restrict__ b1p,
                                                 const float* __restrict__ b2p,
                                                 void* __restrict__ out0,
                                                 void* __restrict__ out1,
                                                 void* __restrict__ out2) {
    __shared__ __align__(16) unsigned short As[128][64];
    __shared__ __align__(16) unsigned short Bs[128][64];
    const int tid = threadIdx.x;
    const int w = tid >> 6, lane = tid & 63;
    const int quad = lane >> 4, ln = lane & 15;
    const int wr = w >> 1, wc = w & 1;

    const int NXB = (MODE == 1) ? 18 : 6;
    const int bx = blockIdx.x;
    const int xcd = bx & 7, slot = bx >> 3;
    const int n0 = (slot % NXB) * 128;
    const int m0 = ((slot / NXB) * 8 + xcd) * 128;

    const int srow = lane >> 3;
    const int ssw = ((lane & 7) ^ srow) * 8;
    const unsigned short* agp[4];
    const unsigned short* bgp[4];
    void* asl[4];
    void* bsl[4];
#pragma unroll
    for (int i = 0; i < 4; ++i) {
        const int R = i * 32 + w * 8;
        agp[i] = A + (size_t)(m0 + R + srow) * CC + ssw;
        bgp[i] = Bw + (size_t)(n0 + R + srow) * CC + ssw;
        asl[i] = &As[R][0];
        bsl[i] = &Bs[R][0];
    }

    floatx4 acc[4][4];
#pragma unroll
    for (int mi = 0; mi < 4; ++mi)
#pragma unroll
        for (int ni = 0; ni < 4; ++ni) acc[mi][ni] = (floatx4){0.f, 0.f, 0.f, 0.f};

    const int ps0 = (quad ^ (ln & 7)) * 8;

    for (int k0 = 0; k0 < CC; k0 += 64) {
        __syncthreads();
#pragma unroll
        for (int i = 0; i < 4; ++i) {
            gl_lds16(agp[i] + k0, asl[i]);
            gl_lds16(bgp[i] + k0, bsl[i]);
        }
        __syncthreads();
#pragma unroll
        for (int kh = 0; kh < 2; ++kh) {
            const int ps = ps0 ^ (kh * 32);
            short8 af[4], bfr[4];
#pragma unroll
            for (int mi = 0; mi < 4; ++mi)
                af[mi] = *(const short8*)&As[wr * 64 + mi * 16 + ln][ps];
#pragma unroll
            for (int ni = 0; ni < 4; ++ni)
                bfr[ni] = *(const short8*)&Bs[wc * 64 + ni * 16 + ln][ps];
#pragma unroll
            for (int mi = 0; mi < 4; ++mi)
#pragma unroll
                for (int ni = 0; ni < 4; ++ni)
                    acc[mi][ni] = __builtin_amdgcn_mfma_f32_16x16x32_bf16(af[mi], bfr[ni], acc[mi][ni], 0, 0, 0);
        }
    }

    if (MODE == 0) {
        float* outf = (float*)out0;
        float bv[4];
#pragma unroll
        for (int ni = 0; ni < 4; ++ni) bv[ni] = b0p[n0 + wc * 64 + ni * 16 + ln];
#pragma unroll
        for (int mi = 0; mi < 4; ++mi)
#pragma unroll
            for (int r = 0; r < 4; ++r) {
                size_t row = m0 + wr * 64 + mi * 16 + quad * 4 + r;
#pragma unroll
                for (int ni = 0; ni < 4; ++ni)
                    outf[row * CC + n0 + wc * 64 + ni * 16 + ln] = acc[mi][ni][r] + bv[ni];
            }
    } else {
        const int seg = n0 / CC;
        const int nl0 = n0 - seg * CC;
        const float* bp = (seg == 0) ? b0p : (seg == 1) ? b1p : b2p;
        float bv[4];
#pragma unroll
        for (int ni = 0; ni < 4; ++ni) bv[ni] = bp[nl0 + wc * 64 + ni * 16 + ln];

        if (seg < 2) {
            unsigned short* outb = (unsigned short*)(seg == 0 ? out0 : out1);
#pragma unroll
            for (int mi = 0; mi < 4; ++mi)
#pragma unroll
                for (int r = 0; r < 4; ++r) {
                    size_t row = m0 + wr * 64 + mi * 16 + quad * 4 + r;
#pragma unroll
                    for (int ni = 0; ni < 4; ++ni)
                        outb[row * CC + nl0 + wc * 64 + ni * 16 + ln] = f2bf(acc[mi][ni][r] + bv[ni]);
                }
        } else {
            unsigned short* outb = (unsigned short*)out2;
            const int b = m0 >> 11;
#pragma unroll
            for (int ni = 0; ni < 4; ++ni) {
                int col = nl0 + wc * 64 + ni * 16 + ln;
                int h = col / HD, d = col % HD;
                size_t base = (size_t)((b * NHD + h) * HD + d) * TT;
#pragma unroll
                for (int mi = 0; mi < 4; ++mi) {
                    int t = (m0 & 2047) + wr * 64 + mi * 16 + quad * 4;
                    ushort4 pk;
                    pk.x = f2bf(acc[mi][ni][0] + bv[ni]);
                    pk.y = f2bf(acc[mi][ni][1] + bv[ni]);
                    pk.z = f2bf(acc[mi][ni][2] + bv[ni]);
                    pk.w = f2bf(acc[mi][ni][3] + bv[ni]);
                    *(ushort4*)(outb + base + t) = pk;
                }
            }
        }
    }
}

// RoPE in-place via precomputed table, vectorized (8 pairs/thread).
__global__ __launch_bounds__(256) void rope_bf(unsigned short* __restrict__ q,
                                               unsigned short* __restrict__ k,
                                               const float2* __restrict__ tab) {
    int idx = blockIdx.x * blockDim.x + threadIdx.x;  // over B*T*H*3
    const int HALF = HD / 2;
    int p8 = idx % 3;
    int rest = idx / 3;
    int h = rest % NHD;
    int n = rest / NHD;        // b*T + t
    int t = n & (TT - 1);
    const float QSC = 0.14433756729740643f * 1.4426950408889634f;
    size_t base = (size_t)n * CC + h * HD + p8 * 8;
    const float2* tp = tab + t * HALF + p8 * 8;

    short8 q1 = *(const short8*)(q + base);
    short8 q2 = *(const short8*)(q + base + HALF);
    short8 k1 = *(const short8*)(k + base);
    short8 k2 = *(const short8*)(k + base + HALF);
    short8 r1, r2, s1, s2;
#pragma unroll
    for (int jj = 0; jj < 8; ++jj) {
        float2 cssn = tp[jj];
        float cs = cssn.x, sn = cssn.y;
        float a = bfu2f((unsigned short)q1[jj]), bb = bfu2f((unsigned short)q2[jj]);
        r1[jj] = (short)f2bf((a * cs - bb * sn) * QSC);
        r2[jj] = (short)f2bf((bb * cs + a * sn) * QSC);
        float c2 = bfu2f((unsigned short)k1[jj]), d2 = bfu2f((unsigned short)k2[jj]);
        s1[jj] = (short)f2bf(c2 * cs - d2 * sn);
        s2[jj] = (short)f2bf(d2 * cs + c2 * sn);
    }
    *(short8*)(q + base) = r1;
    *(short8*)(q + base + HALF) = r2;
    *(short8*)(k + base) = s1;
    *(short8*)(k + base + HALF) = s2;
}

// MFMA flash attention, exp2-domain, fixed softmax reference (m=0).
// Round-4 structure: 128 q-rows per block (two 64-row groups a/b per wave:
// each wave owns 32 q-rows), so every K/V fragment read from LDS feeds TWO
// MFMAs -> LDS bytes per q-row drop 0.61x vs the 64-row block. K and V live
// in LDS (XOR-swizzled, [64] cols); both barriers are lgkm-only so the K/V
// register prefetch stays in flight. Q direct from global (8 VGPR/group).
// Grid 512 = 64 (b,h) x 8 pairs; pair schedule (qt, 15-qt) = exactly 34
// k-steps per block; XCD-pinned -> exactly 2 blocks/CU, zero tail.
// launch_bounds(256,2): grid only needs 2 blocks/CU resident, so give the
// allocator a 256-VGPR cap -- eliminates the spill failure mode that burned
// rounds 1-3 (WRITE_SIZE is the tripwire: must stay ~12.5 MB).
__global__ __launch_bounds__(256, 2) void attn_kernel(const unsigned short* __restrict__ qb,
                                                      const unsigned short* __restrict__ kb,
                                                      const unsigned short* __restrict__ vt,
                                                      const float* __restrict__ amask,
                                                      unsigned short* __restrict__ ctx) {
    const int bx = blockIdx.x;
    const int xcd = bx & 7;
    const int rem = bx >> 3;                // [0,64)
    const int pair = rem & 7;
    const int j = ((rem >> 3) << 3) | xcd;  // (b,h) group, grouped per XCD
    const int b = j >> 4, h = j & 15;
    const int tid = threadIdx.x;
    const int w = tid >> 6, lane = tid & 63;
    const int g = lane >> 4, ln = lane & 15;
    const int sw = ln & 7;

    __shared__ __align__(16) unsigned short Ks[64][64];
    __shared__ __align__(16) unsigned short Vs[48][64];
    __shared__ __align__(16) unsigned short Pw[4][32][64];
    __shared__ __align__(16) float l_s[4][32];

    const short8 z8 = {0, 0, 0, 0, 0, 0, 0, 0};
    const short8 ones8 = {0x3F80, 0x3F80, 0x3F80, 0x3F80, 0x3F80, 0x3F80, 0x3F80, 0x3F80};

    // zero Ks pad units 6,7 (XOR-swizzled) once; unit-6 elem 0 = mask slot
    // (rewritten each step), elems 1..7 and unit 7 stay 0.
    if (tid < 128) {
        int rr = tid >> 1, half = tid & 1;
        *(short8*)&Ks[rr][((6 + half) ^ (rr & 7)) * 8] = z8;
    }

    // K stage: 64 rows x 6 units (48 cols). V stage: 48 rows x 8 units (64 cols).
    const int ck1 = tid + 256;
    const int rK0 = tid / 6, sK0 = tid % 6;
    const int rK1 = ck1 / 6, sK1 = ck1 % 6;
    const int swK0 = (sK0 ^ (rK0 & 7)) * 8;
    const int swK1 = (sK1 ^ (rK1 & 7)) * 8;
    const int rV0 = tid >> 3, sV0 = tid & 7;   // rows 0..31
    const int rV1 = rV0 + 32;                  // tid<128: rows 32..47
    const int swV0 = (sV0 ^ (rV0 & 7)) * 8;
    const int swV1 = (sV0 ^ (rV1 & 7)) * 8;

    const unsigned short* kbase0 = kb + (size_t)(b * TT + rK0) * CC + h * HD + sK0 * 8;
    const unsigned short* kbase1 = kb + (size_t)(b * TT + rK1) * CC + h * HD + sK1 * 8;
    const unsigned short* vbase0 = vt + ((size_t)((b * NHD + h) * HD) + rV0) * TT + sV0 * 8;
    const unsigned short* vbase1 = vbase0 + (size_t)32 * TT;
    const float* mbase = amask + b * TT + (tid & 63);
    const float MBS = -10000.0f * 1.4426950408889634f;
    const int mcol = (6 ^ (lane & 7)) * 8;     // swizzled mask slot (row = lane)
    const short8 vone = (ln == 0) ? ones8 : z8;  // ones-column B-frag (l accumulator)

    for (int rep = 0; rep < 2; ++rep) {
        const int qt = rep ? (NQT2 - 1 - pair) : pair;
        const int q0 = qt * 128;
        const int last = 2 * qt + 1;

        // Q fragments straight from global, two row-groups per wave.
        const unsigned short* qrA = qb + (size_t)(b * TT + q0 + w * 16 + ln) * CC + h * HD;
        const unsigned short* qrB = qrA + (size_t)64 * CC;
        short8 aq0a = *(const short8*)(qrA + g * 8);
        short8 aq0b = *(const short8*)(qrB + g * 8);
        short8 aq1a, aq1b;
        if (g < 2) {
            aq1a = *(const short8*)(qrA + 32 + g * 8);
            aq1b = *(const short8*)(qrB + 32 + g * 8);
        } else {
            aq1a = z8; aq1b = z8;
            if (g == 2) { aq1a[0] = (short)0x3F80; aq1b[0] = (short)0x3F80; }
        }

        const unsigned short* kp0 = kbase0;
        const unsigned short* kp1 = kbase1;
        const unsigned short* vp0 = vbase0;
        const unsigned short* vp1 = vbase1;
        const float* mp = mbase;

        short8 kr0, kr1, vr0, vr1;
        float mr = 1.0f;
        kr0 = *(const short8*)kp0;
        vr0 = *(const short8*)vp0;
        if (tid < 128) { kr1 = *(const short8*)kp1; vr1 = *(const short8*)vp1; }
        if (tid < 64) mr = *mp;

        const int qlA = q0 + w * 16 + ln;
        const int qlB = qlA + 64;
        floatx4 oa0 = {0.f, 0.f, 0.f, 0.f}, oa1 = oa0, oa2 = oa0, oa3 = oa0;
        floatx4 ob0 = oa0, ob1 = oa0, ob2 = oa0, ob3 = oa0;

        for (int kt = 0; kt <= last; ++kt) {
            HOT_BARRIER();   // prior step's (or prior rep's) LDS reads complete
            *(short8*)&Ks[rK0][swK0] = kr0;
            *(short8*)&Vs[rV0][swV0] = vr0;
            if (tid < 128) {
                *(short8*)&Ks[rK1][swK1] = kr1;
                *(short8*)&Vs[rV1][swV1] = vr1;
            }
            if (tid < 64) Ks[lane][mcol] = f2bf((1.0f - mr) * MBS);
            HOT_BARRIER();   // writes visible; vmcnt NOT drained

            if (kt < last) {
                kp0 += (size_t)64 * CC; kr0 = *(const short8*)kp0;
                vp0 += 64;              vr0 = *(const short8*)vp0;
                if (tid < 128) {
                    kp1 += (size_t)64 * CC; kr1 = *(const short8*)kp1;
                    vp1 += 64;              vr1 = *(const short8*)vp1;
                }
                if (tid < 64) { mp += 64; mr = *mp; }
            }

            const int k0 = kt * 64;
            const bool a_act = (kt <= 2 * qt);
            const bool diagA = (kt == 2 * qt);
            const bool diagB = (kt == last);

            // QK^T: each K fragment read feeds BOTH q-groups.
            floatx4 sa[4], sb[4];
#pragma unroll
            for (int c = 0; c < 4; ++c) {
                short8 kf0 = *(const short8*)&Ks[c * 16 + ln][(g ^ sw) * 8];
                short8 kf1 = *(const short8*)&Ks[c * 16 + ln][((4 + g) ^ sw) * 8];
                floatx4 z = {0.f, 0.f, 0.f, 0.f};
                if (a_act) {
                    floatx4 za = __builtin_amdgcn_mfma_f32_16x16x32_bf16(kf0, aq0a, z, 0, 0, 0);
                    sa[c] = __builtin_amdgcn_mfma_f32_16x16x32_bf16(kf1, aq1a, za, 0, 0, 0);
                }
                floatx4 zb = __builtin_amdgcn_mfma_f32_16x16x32_bf16(kf0, aq0b, z, 0, 0, 0);
                sb[c] = __builtin_amdgcn_mfma_f32_16x16x32_bf16(kf1, aq1b, zb, 0, 0, 0);
            }

            // softmax (exp2-domain) + pack into Pw; group a rows [ln], b rows [16+ln]
            if (a_act) {
#pragma unroll
                for (int c = 0; c < 4; ++c) {
                    float pv[4];
#pragma unroll
                    for (int r = 0; r < 4; ++r) {
                        float e = __builtin_amdgcn_exp2f(sa[c][r]);
                        if (diagA && (k0 + c * 16 + g * 4 + r > qlA)) e = 0.f;
                        pv[r] = e;
                    }
                    uint2 pk;
                    pk.x = pk_bf2(pv[0], pv[1]);
                    pk.y = pk_bf2(pv[2], pv[3]);
                    *(uint2*)&Pw[w][ln][((2 * c + (g >> 1)) ^ sw) * 8 + (g & 1) * 4] = pk;
                }
            }
#pragma unroll
            for (int c = 0; c < 4; ++c) {
                float pv[4];
#pragma unroll
                for (int r = 0; r < 4; ++r) {
                    float e = __builtin_amdgcn_exp2f(sb[c][r]);
                    if (diagB && (k0 + c * 16 + g * 4 + r > qlB)) e = 0.f;
                    pv[r] = e;
                }
                uint2 pk;
                pk.x = pk_bf2(pv[0], pv[1]);
                pk.y = pk_bf2(pv[2], pv[3]);
                *(uint2*)&Pw[w][16 + ln][((2 * c + (g >> 1)) ^ sw) * 8 + (g & 1) * 4] = pk;
            }

            short8 pa0a, pa1a;
            if (a_act) {
                pa0a = *(const short8*)&Pw[w][ln][(g ^ sw) * 8];
                pa1a = *(const short8*)&Pw[w][ln][((4 + g) ^ sw) * 8];
            }
            short8 pa0b = *(const short8*)&Pw[w][16 + ln][(g ^ sw) * 8];
            short8 pa1b = *(const short8*)&Pw[w][16 + ln][((4 + g) ^ sw) * 8];

            // PV: each V fragment read feeds BOTH q-groups.
#pragma unroll
            for (int n = 0; n < 3; ++n) {
                short8 vb0 = *(const short8*)&Vs[n * 16 + ln][(g ^ sw) * 8];
                short8 vb1 = *(const short8*)&Vs[n * 16 + ln][((4 + g) ^ sw) * 8];
                if (a_act) {
                    floatx4 acc = (n == 0) ? oa0 : (n == 1) ? oa1 : oa2;
                    acc = __builtin_amdgcn_mfma_f32_16x16x32_bf16(pa0a, vb0, acc, 0, 0, 0);
                    acc = __builtin_amdgcn_mfma_f32_16x16x32_bf16(pa1a, vb1, acc, 0, 0, 0);
                    if (n == 0) oa0 = acc; else if (n == 1) oa1 = acc; else oa2 = acc;
                }
                floatx4 accb = (n == 0) ? ob0 : (n == 1) ? ob1 : ob2;
                accb = __builtin_amdgcn_mfma_f32_16x16x32_bf16(pa0b, vb0, accb, 0, 0, 0);
                accb = __builtin_amdgcn_mfma_f32_16x16x32_bf16(pa1b, vb1, accb, 0, 0, 0);
                if (n == 0) ob0 = accb; else if (n == 1) ob1 = accb; else ob2 = accb;
            }
            if (a_act) {
                oa3 = __builtin_amdgcn_mfma_f32_16x16x32_bf16(pa0a, vone, oa3, 0, 0, 0);
                oa3 = __builtin_amdgcn_mfma_f32_16x16x32_bf16(pa1a, vone, oa3, 0, 0, 0);
            }
            ob3 = __builtin_amdgcn_mfma_f32_16x16x32_bf16(pa0b, vone, ob3, 0, 0, 0);
            ob3 = __builtin_amdgcn_mfma_f32_16x16x32_bf16(pa1b, vone, ob3, 0, 0, 0);
        }

        if (ln == 0) {
            *(floatx4*)&l_s[w][g * 4] = oa3;          // per-wave region, no barrier
            *(floatx4*)&l_s[w][16 + g * 4] = ob3;
        }
        floatx4 l4a = *(const floatx4*)&l_s[w][g * 4];
        floatx4 l4b = *(const floatx4*)&l_s[w][16 + g * 4];
#pragma unroll
        for (int r = 0; r < 4; ++r) {
            float invA = 1.0f / l4a[r];
            int t = q0 + w * 16 + g * 4 + r;
            unsigned short* dst = ctx + (size_t)(b * TT + t) * CC + h * HD;
            dst[ln] = f2bf(oa0[r] * invA);
            dst[16 + ln] = f2bf(oa1[r] * invA);
            dst[32 + ln] = f2bf(oa2[r] * invA);
            float invB = 1.0f / l4b[r];
            unsigned short* dstB = dst + (size_t)64 * CC;
            dstB[ln] = f2bf(ob0[r] * invB);
            dstB[16 + ln] = f2bf(ob1[r] * invB);
            dstB[32 + ln] = f2bf(ob2[r] * invB);
        }
    }
}

extern "C" void kernel_launch(void* const* d_in, const int* in_sizes, int n_in,
                              void* d_out, int out_size, void* d_ws, size_t ws_size,
                              hipStream_t stream) {
    const float* hs = (const float*)d_in[0];
    const float* amask = (const float*)d_in[1];
    const float* Wq = (const float*)d_in[2];
    const float* bq = (const float*)d_in[3];
    const float* Wk = (const float*)d_in[4];
    const float* bk = (const float*)d_in[5];
    const float* Wv = (const float*)d_in[6];
    const float* bv = (const float*)d_in[7];
    const float* Wo = (const float*)d_in[8];
    const float* bo = (const float*)d_in[9];

    const size_t NELEM = (size_t)BB * TT * CC;  // 6291456
    const size_t WELEM = (size_t)CC * CC;       // 589824
    unsigned short* hb  = (unsigned short*)d_ws;
    unsigned short* qbuf = hb + NELEM;
    unsigned short* kbuf = qbuf + NELEM;
    unsigned short* vtb = kbuf + NELEM;   // bf16 [B,H,D,T]
    unsigned short* ctxb = vtb + NELEM;
    unsigned short* wqb = ctxb + NELEM;   // wq/wk/wv contiguous = stacked [2304][768]
    unsigned short* wkb = wqb + WELEM;
    unsigned short* wvb = wkb + WELEM;
    unsigned short* wob = wvb + WELEM;
    float2* ropetab = (float2*)(wob + WELEM);  // [2048][24]

    cast_hs<<<NELEM / 1024, 256, 0, stream>>>(hs, hb);
    dim3 wgrid(WELEM / 1024, 4);
    cast_w4<<<wgrid, 256, 0, stream>>>(Wq, Wk, Wv, Wo, wqb, wkb, wvb, wob);
    rope_table<<<(TT * (HD / 2)) / 256, 256, 0, stream>>>(ropetab);

    gemm_mfma<1><<<18 * 64, 256, 0, stream>>>(hb, wqb, bq, bk, bv, qbuf, kbuf, vtb);

    int rope_total = BB * TT * NHD * 3;  // 8 pairs per thread
    rope_bf<<<rope_total / 256, 256, 0, stream>>>(qbuf, kbuf, ropetab);

    attn_kernel<<<512, 256, 0, stream>>>(qbuf, kbuf, vtb, amask, ctxb);

    gemm_mfma<0><<<6 * 64, 256, 0, stream>>>(ctxb, wob, bo, nullptr, nullptr,
                                             (float*)d_out, nullptr, nullptr);
}